// Round 11
// baseline (2017.537 us; speedup 1.0000x reference)
//
#include <hip/hip_runtime.h>

// lstm_seq2seq fused persistent kernel for MI355X (gfx950), R11.
// INTRA-WAVE PIPELINED SETS: the WG's 64 rows split into set0 (rows 0-31)
// and set1 (rows 32-63), half a step apart. Each iteration:
//   phase B: MFMA(set0, t)  source-interleaved with  EW(set1, t-1)
//   phase D: MFMA(set1, t)  source-interleaved with  EW(set0, t)
// MFMA + EW live in ONE instruction stream per wave -> matrix pipe and VALU
// co-issue by construction (no runtime phase-holding, which failed in
// R4/R9/R10). Sync: two 8-flag gates per iteration (fB/fD). set0 h is
// parity double-buffered; set1 h single-buffered (written then read within
// the same iteration, ordered by gate C).
// Cost: weights streamed once per phase (1.15 MB/CU/iter, L2-resident);
// each phase is stream-bound ~576KB/(51-64 B/cyc) under which MFMA and EW hide.
// Carried from R8: A=weights (L2, wave-packed), c in regs, decoder feedback
// folded into weights, K=288 aug ("1" col = bias), log2e fold, kt=0 C=0.

#define SEQ  20
#define TLEN 30
#define LOG2E  1.442695041f
#define LOG2E2 2.885390082f

typedef _Float16 half8   __attribute__((ext_vector_type(8)));
typedef _Float16 half4   __attribute__((ext_vector_type(4)));
typedef _Float16 half2v  __attribute__((ext_vector_type(2)));
typedef float    floatx4 __attribute__((ext_vector_type(4)));

// Packed weights (same layout as R8). Gate row n (0..1023), k (0..287):
//   g=n>>8, c=(n>>4)&15, l16=n&15, w=c>>1, cc=c&1, i=cc*4+g,
//   kt=k>>5, q=(k>>3)&3, j=k&7
//   dst = ((w*9+kt)*8 + i)*512 + q*128 + l16*8 + j
__device__ _Float16 g_w_enc[1024 * 288];
__device__ _Float16 g_w_dec0[1024 * 288];
__device__ _Float16 g_w_deff[1024 * 288];
__device__ _Float16 g_wout[512];           // W_out [2][256] f16 (unscaled)

__global__ void prep_kernel(const float* __restrict__ W_emb,
                            const float* __restrict__ b_emb,
                            const float* __restrict__ W_ih_enc,
                            const float* __restrict__ W_hh_enc,
                            const float* __restrict__ b_enc,
                            const float* __restrict__ W_ih_dec,
                            const float* __restrict__ W_hh_dec,
                            const float* __restrict__ b_dec,
                            const float* __restrict__ W_out,
                            const float* __restrict__ b_out) {
    int gid = blockIdx.x * blockDim.x + threadIdx.x;
    int stride = gridDim.x * blockDim.x;
    for (int s = gid; s < 1024 * 288; s += stride) {
        int n = s / 288, k = s - n * 288;
        int g = n >> 8, c = (n >> 4) & 15, l16 = n & 15;
        int w = c >> 1, cc = c & 1;
        int i = cc * 4 + g;
        int kt = k >> 5, q = (k >> 3) & 3, j = k & 7;
        int dst = ((w * 9 + kt) * 8 + i) * 512 + q * 128 + l16 * 8 + j;
        float sc = (g == 2) ? LOG2E2 : LOG2E;   // exp2-folded row scale
        float fe = 0.f, fd = 0.f, ff = 0.f;
        if (k < 256) {
            fe = W_hh_enc[n * 256 + k];
            fd = W_hh_dec[n * 256 + k];
            ff = fd + W_ih_dec[2 * n] * W_out[k]
                    + W_ih_dec[2 * n + 1] * W_out[256 + k];
        } else {
            int kp = k - 256;
            if (kp < 2) {
                fd = W_ih_dec[2 * n + kp];
                const float* wr = &W_ih_enc[n * 64];
                for (int e = 0; e < 64; e++) fe = fmaf(wr[e], W_emb[2 * e + kp], fe);
            } else if (kp == 2) {
                fd = b_dec[n];
                ff = b_dec[n] + W_ih_dec[2 * n] * b_out[0]
                              + W_ih_dec[2 * n + 1] * b_out[1];
                fe = b_enc[n];
                const float* wr = &W_ih_enc[n * 64];
                for (int e = 0; e < 64; e++) fe = fmaf(wr[e], b_emb[e], fe);
            }
        }
        g_w_enc[dst]  = (_Float16)(fe * sc);
        g_w_dec0[dst] = (_Float16)(fd * sc);
        g_w_deff[dst] = (_Float16)(ff * sc);
    }
    if (gid < 512) g_wout[gid] = (_Float16)W_out[gid];
}

__global__ __launch_bounds__(512, 2) void lstm_fused(
        const float* __restrict__ x_input,    // [20][16384][2]
        const float* __restrict__ b_out,      // [2]
        float* __restrict__ out)              // [30][16384][2]
{
    // set0 h: parity double-buffer; set1 h: single buffer.
    // layout per set: [ntl(2)][kt(9)][512] halves; kt=8 = aug (x0,x1,"1").
    __shared__ __align__(16) _Float16 h0[2][9216];              // 36864 B
    __shared__ __align__(16) _Float16 h1[9216];                 // 18432 B
    __shared__ __align__(16) float    partial_lds[2][2][8 * 68];// 8704 B
    __shared__ int fB[8];   // wave w finished phase B of iter fB[w]
    __shared__ int fD[8];   // wave w finished phase D of iter fD[w]-1
    __shared__ int cnt[2][2];

    const int tid = threadIdx.x;
    const int w   = tid >> 6;
    const int L   = tid & 63;
    const int l16 = L & 15;
    const int q   = L >> 4;
    const long row0 = (long)blockIdx.x * 64;

    // ---- init ----
    {
        int* hz = (int*)&h0[0][0];
        for (int idx = tid; idx < 9216; idx += 512) hz[idx] = 0;   // both h0 bufs
        int* hz1 = (int*)&h1[0];
        for (int idx = tid; idx < 4608; idx += 512) hz1[idx] = 0;
        if (tid < 8) { fB[tid] = -1; fD[tid] = 0; }
        if (tid < 4) cnt[tid >> 1][tid & 1] = 0;
    }
    __syncthreads();
    // "1" columns (j=2 of aug tile) + x(0)
    if (tid < 64) {
        int buf = tid >> 5, bl = tid & 31;
        h0[buf][((bl >> 4) * 9 + 8) * 512 + (bl & 15) * 8 + 2] = (_Float16)1.f;
        if (buf == 0)
            h1[((bl >> 4) * 9 + 8) * 512 + (bl & 15) * 8 + 2] = (_Float16)1.f;
    }
    if (tid < 128) {
        int b = tid >> 1, jj = tid & 1;
        float xv = x_input[(row0 + b) * 2 + jj];
        if (b < 32)
            h0[0][((b >> 4) * 9 + 8) * 512 + (b & 15) * 8 + jj] = (_Float16)xv;
        else {
            int bl = b - 32;
            h1[((bl >> 4) * 9 + 8) * 512 + (bl & 15) * 8 + jj] = (_Float16)xv;
        }
    }

    const float boL = b_out[L & 1];
    const int aoff = q * 128 + l16 * 8;
    const _Float16* __restrict__ wenc_w  = &g_w_enc[w * 36864];
    const _Float16* __restrict__ wdec0_w = &g_w_dec0[w * 36864];
    const _Float16* __restrict__ wdeff_w = &g_w_deff[w * 36864];

    _Float16 wo[2][2][4];   // [jj][cc][r] for cells 32w+16cc+4q+r
#pragma unroll
    for (int jj = 0; jj < 2; jj++)
#pragma unroll
        for (int cc = 0; cc < 2; cc++)
#pragma unroll
            for (int r = 0; r < 4; r++)
                wo[jj][cc][r] = g_wout[jj * 256 + 32 * w + 16 * cc + 4 * q + r];

    floatx4 acc0[8][2], acc1[8][2];   // [i=cc*4+g][ntl]
    float   c0[2][2][4], c1[2][2][4]; // [ntl][cc][r]
#pragma unroll
    for (int ntl = 0; ntl < 2; ntl++)
#pragma unroll
        for (int cc = 0; cc < 2; cc++)
#pragma unroll
            for (int r = 0; r < 4; r++) { c0[ntl][cc][r] = 0.f; c1[ntl][cc][r] = 0.f; }

    __syncthreads();   // the ONLY barrier

    auto gate = [&](int* arr, int tv) {
        for (;;) {
            bool ok = true;
#pragma unroll
            for (int i8 = 0; i8 < 8; i8++)
                ok &= (__hip_atomic_load(&arr[i8], __ATOMIC_ACQUIRE,
                                         __HIP_MEMORY_SCOPE_WORKGROUP) >= tv);
            if (ok) break;
            __builtin_amdgcn_s_sleep(1);
        }
        __builtin_amdgcn_sched_barrier(0);
    };
    auto publish = [&](int* p, int v) {
        if (L == 0)
            __hip_atomic_store(p, v, __ATOMIC_RELEASE,
                               __HIP_MEMORY_SCOPE_WORKGROUP);
    };
    auto wsel = [&](int t) {
        return (t < SEQ) ? wenc_w : (t == SEQ) ? wdec0_w : wdeff_w;
    };

    // EW unit: one (ntl,cc) chunk of a set. acc/c/hn set-specific; 'step' is
    // the LSTM step whose h is being produced (for the out guard).
    auto ew_unit = [&](floatx4 (&acc)[8][2], float (&cst)[2][2][4],
                       _Float16* hn, float (&po)[2][2], int ntl, int cc,
                       bool do_po) {
        half4 hv4;
        float hvf[4];
#pragma unroll
        for (int r = 0; r < 4; r++) {
            float ai = acc[cc * 4 + 0][ntl][r];
            float af = acc[cc * 4 + 1][ntl][r];
            float ag = acc[cc * 4 + 2][ntl][r];
            float ao = acc[cc * 4 + 3][ntl][r];
            float eI = __builtin_amdgcn_exp2f(-ai);
            float eG = __builtin_amdgcn_exp2f(-ag);
            float eF = __builtin_amdgcn_exp2f(-af);
            float eO = __builtin_amdgcn_exp2f(-ao);
            float ig = (1.f - eG) *
                __builtin_amdgcn_rcpf((1.f + eI) * (1.f + eG));
            float fs = __builtin_amdgcn_rcpf(1.f + eF);
            float cn = fmaf(fs, cst[ntl][cc][r], ig);
            cst[ntl][cc][r] = cn;
            float cnc = fminf(fmaxf(cn, -12.f), 12.f);
            float eC = __builtin_amdgcn_exp2f(-LOG2E2 * cnc);
            float hv = (1.f - eC) *
                __builtin_amdgcn_rcpf((1.f + eO) * (1.f + eC));
            hvf[r] = hv;
            hv4[r] = (_Float16)hv;
        }
        *(half4*)&hn[(ntl * 9 + w) * 512 + (2 * cc + (q >> 1)) * 128 +
                     l16 * 8 + 4 * (q & 1)] = hv4;
        if (do_po) {
#pragma unroll
            for (int r = 0; r < 4; r++) {
                po[ntl][0] = fmaf(hvf[r], (float)wo[0][cc][r], po[ntl][0]);
                po[ntl][1] = fmaf(hvf[r], (float)wo[1][cc][r], po[ntl][1]);
            }
        }
    };

    // out-projection finalize for a set (32 rows), called by every wave.
    auto out_reduce = [&](float (&po)[2][2], int set, int par, int step) {
#pragma unroll
        for (int ntl = 0; ntl < 2; ntl++)
#pragma unroll
            for (int jj = 0; jj < 2; jj++) {
                float s = po[ntl][jj];
                s += __shfl_xor(s, 16);
                s += __shfl_xor(s, 32);
                po[ntl][jj] = s;
            }
        if (q == 0) {
            float* pl = &partial_lds[set][par][w * 68];
#pragma unroll
            for (int ntl = 0; ntl < 2; ntl++) {
                pl[ntl * 16 + l16]      = po[ntl][0];
                pl[34 + ntl * 16 + l16] = po[ntl][1];
            }
        }
        __threadfence_block();
        int arr = 0;
        if (L == 0) arr = atomicAdd(&cnt[set][par], 1);
        arr = __shfl(arr, 0);
        if (arr == 7) {
            if (L == 0)
                __hip_atomic_store(&cnt[set][par], 0, __ATOMIC_RELAXED,
                                   __HIP_MEMORY_SCOPE_WORKGROUP);
            __threadfence_block();
            int r = L >> 1, jj = L & 1;
            float s = boL;
            const float* pl = &partial_lds[set][par][jj * 34 + r];
#pragma unroll
            for (int w8 = 0; w8 < 8; w8++) s += pl[w8 * 68];
            out[(long)(step - SEQ) * 32768 + (row0 + set * 32 + r) * 2 + jj] = s;
        }
    };

    // ---- phase B: MFMA(set0,t) ⊗ EW(set1,t-1) ----
    auto phaseB = [&](int t, bool mm, bool ew) {
        gate(fD, t);
        const _Float16* __restrict__ Wb = wsel(t);
        const _Float16* __restrict__ hp0 = h0[t & 1];
        float po1[2][2] = {{0.f, 0.f}, {0.f, 0.f}};
        const bool do_po1 = ew && (t >= SEQ + 1);
        // prefetch set1's x for step t (consumed at tail)
        float2 xv2 = make_float2(0.f, 0.f);
        const bool do_x1 = ew && (t <= SEQ - 1) && (w == 0) && (L < 32);
        if (do_x1)
            xv2 = *(const float2*)&x_input[(long)t * 32768 + (row0 + 32 + L) * 2];
        if (mm) {
#pragma unroll
            for (int kt = 0; kt < 9; kt++) {
                half8 B0 = *(const half8*)&hp0[kt * 512 + aoff];
                half8 B1 = *(const half8*)&hp0[(9 + kt) * 512 + aoff];
#pragma unroll
                for (int i = 0; i < 8; i++) {
                    half8 Aw = *(const half8*)&Wb[(kt * 8 + i) * 512 + aoff];
                    if (kt == 0) {
                        acc0[i][0] = __builtin_amdgcn_mfma_f32_16x16x32_f16(
                            Aw, B0, (floatx4)(0.f), 0, 0, 0);
                        acc0[i][1] = __builtin_amdgcn_mfma_f32_16x16x32_f16(
                            Aw, B1, (floatx4)(0.f), 0, 0, 0);
                    } else {
                        acc0[i][0] = __builtin_amdgcn_mfma_f32_16x16x32_f16(
                            Aw, B0, acc0[i][0], 0, 0, 0);
                        acc0[i][1] = __builtin_amdgcn_mfma_f32_16x16x32_f16(
                            Aw, B1, acc0[i][1], 0, 0, 0);
                    }
                }
                if (ew && kt >= 1 && kt <= 4)   // interleave: EW1 units 0..3
                    ew_unit(acc1, c1, h1, po1, (kt - 1) & 1, (kt - 1) >> 1, do_po1);
            }
        } else if (ew) {
#pragma unroll
            for (int u = 0; u < 4; u++)
                ew_unit(acc1, c1, h1, po1, u & 1, u >> 1, do_po1);
        }
        if (do_x1) {
            half2v xh; xh[0] = (_Float16)xv2.x; xh[1] = (_Float16)xv2.y;
            *(half2v*)&h1[((L >> 4) * 9 + 8) * 512 + (L & 15) * 8] = xh;
        }
        publish(&fB[w], t);
        if (do_po1) out_reduce(po1, 1, t & 1, t - 1);
    };

    // ---- phase D: MFMA(set1,t) ⊗ EW(set0,t) ----
    auto phaseD = [&](int t) {
        gate(fB, t);
        const _Float16* __restrict__ Wb = wsel(t);
        _Float16* __restrict__ hn0 = h0[(t + 1) & 1];
        float po0[2][2] = {{0.f, 0.f}, {0.f, 0.f}};
        const bool do_po0 = (t >= SEQ);
        float2 xv2 = make_float2(0.f, 0.f);
        const bool do_x0 = (t <= SEQ - 1) && (w == 0) && (L < 32);
        if (do_x0) {
            int srct = (t + 1 < SEQ) ? t + 1 : SEQ - 1;
            xv2 = *(const float2*)&x_input[(long)srct * 32768 + (row0 + L) * 2];
        }
#pragma unroll
        for (int kt = 0; kt < 9; kt++) {
            half8 B0 = *(const half8*)&h1[kt * 512 + aoff];
            half8 B1 = *(const half8*)&h1[(9 + kt) * 512 + aoff];
#pragma unroll
            for (int i = 0; i < 8; i++) {
                half8 Aw = *(const half8*)&Wb[(kt * 8 + i) * 512 + aoff];
                if (kt == 0) {
                    acc1[i][0] = __builtin_amdgcn_mfma_f32_16x16x32_f16(
                        Aw, B0, (floatx4)(0.f), 0, 0, 0);
                    acc1[i][1] = __builtin_amdgcn_mfma_f32_16x16x32_f16(
                        Aw, B1, (floatx4)(0.f), 0, 0, 0);
                } else {
                    acc1[i][0] = __builtin_amdgcn_mfma_f32_16x16x32_f16(
                        Aw, B0, acc1[i][0], 0, 0, 0);
                    acc1[i][1] = __builtin_amdgcn_mfma_f32_16x16x32_f16(
                        Aw, B1, acc1[i][1], 0, 0, 0);
                }
            }
            if (kt >= 1 && kt <= 4)   // interleave: EW0 units 0..3
                ew_unit(acc0, c0, hn0, po0, (kt - 1) & 1, (kt - 1) >> 1, do_po0);
        }
        if (do_x0) {
            half2v xh; xh[0] = (_Float16)xv2.x; xh[1] = (_Float16)xv2.y;
            *(half2v*)&hn0[((L >> 4) * 9 + 8) * 512 + (L & 15) * 8] = xh;
        }
        publish(&fD[w], t + 1);
        if (do_po0) out_reduce(po0, 0, t & 1, t);
    };

    // ---- pipeline: prologue, steady loop, epilogue ----
    phaseB(0, true, false);
    phaseD(0);
#pragma unroll 1
    for (int t = 1; t <= SEQ + TLEN - 1; t++) {
        phaseB(t, true, true);
        phaseD(t);
    }
    phaseB(SEQ + TLEN, false, true);   // flush: EW1(49) + out1 step 49
}

extern "C" void kernel_launch(void* const* d_in, const int* in_sizes, int n_in,
                              void* d_out, int out_size, void* d_ws, size_t ws_size,
                              hipStream_t stream) {
    (void)in_sizes; (void)n_in; (void)d_ws; (void)ws_size; (void)out_size;
    const float* x      = (const float*)d_in[0];
    const float* W_emb  = (const float*)d_in[1];
    const float* b_emb  = (const float*)d_in[2];
    const float* W_ih_e = (const float*)d_in[3];
    const float* W_hh_e = (const float*)d_in[4];
    const float* b_enc  = (const float*)d_in[5];
    const float* W_ih_d = (const float*)d_in[6];
    const float* W_hh_d = (const float*)d_in[7];
    const float* b_dec  = (const float*)d_in[8];
    const float* W_out  = (const float*)d_in[9];
    const float* b_out  = (const float*)d_in[10];
    float* outp = (float*)d_out;

    prep_kernel<<<512, 256, 0, stream>>>(W_emb, b_emb, W_ih_e, W_hh_e, b_enc,
                                         W_ih_d, W_hh_d, b_dec, W_out, b_out);
    lstm_fused<<<256, 512, 0, stream>>>(x, b_out, outp);
}

// Round 12
// 831.265 us; speedup vs baseline: 2.4271x; 2.4271x over previous
//
#include <hip/hip_runtime.h>

// lstm_seq2seq fused persistent kernel for MI355X (gfx950), R12.
// WAVE SPECIALIZATION: waves 0-3 = MFMA-only (matrix pipe), waves 4-7 =
// EW-only (VALU/trans pipe); one of each per SIMD -> m114 co-issue.
// Gates flow MFMA->EW via a 2-deep LDS f16 ring of quarter-step chunks;
// h is parity double-buffered. Dependency-forced pipeline (no voluntary
// phase gates - R10's failure), split register budgets (no R11 spill):
// MFMA wave: acc 64 AGPR/quarter + ~110 arch; EW wave: ~180 arch, no acc.
// MFMA(t) consumes h(t-1) kt-tiles in EW's production order {0,2,4,6,1,3,5,7,8}
// with per-tile flags on quarter 0 only (all tiles ready by its end).
// Carried: A=weights streamed from L2 (per-(wave,quarter,kt) contiguous
// packing), decoder feedback folded, K=288 aug ("1"=bias col), log2e fold,
// kt=0 literal-zero C.

#define SEQ  20
#define TLEN 30
#define LOG2E  1.442695041f
#define LOG2E2 2.885390082f

typedef _Float16 half8   __attribute__((ext_vector_type(8)));
typedef _Float16 half4   __attribute__((ext_vector_type(4)));
typedef _Float16 half2v  __attribute__((ext_vector_type(2)));
typedef float    floatx4 __attribute__((ext_vector_type(4)));

// Packed weights. Gate row n (0..1023), k (0..287):
//   g=n>>8 (gate type), rem=n&255, pw=rem>>6 (MFMA wave), r=(rem>>5)&1,
//   u=(rem>>4)&1, qi=2r+u (quarter), l16=n&15; kt=k>>5, q=(k>>3)&3, j8=k&7
//   dst = (((pw*4+qi)*9 + kt)*4 + g)*512 + q*128 + l16*8 + j8
// => per (pw,qi,kt): 4 contiguous 1KB A-fragments.
__device__ _Float16 g_w_enc[1024 * 288];
__device__ _Float16 g_w_dec0[1024 * 288];
__device__ _Float16 g_w_deff[1024 * 288];
__device__ _Float16 g_wout[512];           // W_out [2][256] f16 (unscaled)

__global__ void prep_kernel(const float* __restrict__ W_emb,
                            const float* __restrict__ b_emb,
                            const float* __restrict__ W_ih_enc,
                            const float* __restrict__ W_hh_enc,
                            const float* __restrict__ b_enc,
                            const float* __restrict__ W_ih_dec,
                            const float* __restrict__ W_hh_dec,
                            const float* __restrict__ b_dec,
                            const float* __restrict__ W_out,
                            const float* __restrict__ b_out) {
    int gid = blockIdx.x * blockDim.x + threadIdx.x;
    int stride = gridDim.x * blockDim.x;
    for (int s = gid; s < 1024 * 288; s += stride) {
        int n = s / 288, k = s - n * 288;
        int g = n >> 8, rem = n & 255, l16 = n & 15;
        int pw = rem >> 6, r = (rem >> 5) & 1, u = (rem >> 4) & 1;
        int qi = 2 * r + u;
        int kt = k >> 5, q = (k >> 3) & 3, j8 = k & 7;
        int dst = (((pw * 4 + qi) * 9 + kt) * 4 + g) * 512 + q * 128 + l16 * 8 + j8;
        float sc = (g == 2) ? LOG2E2 : LOG2E;
        float fe = 0.f, fd = 0.f, ff = 0.f;
        if (k < 256) {
            fe = W_hh_enc[n * 256 + k];
            fd = W_hh_dec[n * 256 + k];
            ff = fd + W_ih_dec[2 * n] * W_out[k]
                    + W_ih_dec[2 * n + 1] * W_out[256 + k];
        } else {
            int kp = k - 256;
            if (kp < 2) {
                fd = W_ih_dec[2 * n + kp];
                const float* wr = &W_ih_enc[n * 64];
                for (int e = 0; e < 64; e++) fe = fmaf(wr[e], W_emb[2 * e + kp], fe);
            } else if (kp == 2) {
                fd = b_dec[n];
                ff = b_dec[n] + W_ih_dec[2 * n] * b_out[0]
                              + W_ih_dec[2 * n + 1] * b_out[1];
                fe = b_enc[n];
                const float* wr = &W_ih_enc[n * 64];
                for (int e = 0; e < 64; e++) fe = fmaf(wr[e], b_emb[e], fe);
            }
        }
        g_w_enc[dst]  = (_Float16)(fe * sc);
        g_w_dec0[dst] = (_Float16)(fd * sc);
        g_w_deff[dst] = (_Float16)(ff * sc);
    }
    if (gid < 512) g_wout[gid] = (_Float16)W_out[gid];
}

__global__ __launch_bounds__(512, 2) void lstm_fused(
        const float* __restrict__ x_input,    // [20][16384][2]
        const float* __restrict__ b_out,      // [2]
        float* __restrict__ out)              // [30][16384][2]
{
    // h(v) lives in buf[v&1]: [nt(4)][kt(9)][512] halves; kt=8 = aug (x,1).
    __shared__ __align__(16) _Float16 h_pack[2][18432];        // 73728 B
    // gates ring: [slot(2)][pair(4)][16 rows x 272] halves (row pad: no bank conflict)
    __shared__ __align__(16) _Float16 gates_ring[2][4][4352];  // 69632 B
    __shared__ __align__(16) float    partial_lds[2][4 * 136]; // 4352 B
    __shared__ int hf[9];      // h kt-tile version flags (EW -> MFMA)
    __shared__ int gprod[4];   // chunks produced per pair (MFMA -> EW)
    __shared__ int gcons[4];   // chunks consumed per pair (EW -> MFMA ring gate)
    __shared__ int cnt[2];     // out-proj arrival counters per parity

    const int tid = threadIdx.x;
    const int w   = tid >> 6;
    const int L   = tid & 63;
    const int l16 = L & 15;
    const int q   = L >> 4;
    const long row0 = (long)blockIdx.x * 64;
    const int aoff = q * 128 + l16 * 8;     // lane offset in a 512-half block
    const int lb   = q * 68 + l16 * 4;      // lane offset in a gates chunk row

    // ---- init ----
    {
        int* hz = (int*)&h_pack[0][0];
        for (int idx = tid; idx < 18432; idx += 512) hz[idx] = 0;  // both bufs
        if (tid < 9) hf[tid] = 0;
        if (tid >= 16 && tid < 20) gprod[tid - 16] = 0;
        if (tid >= 32 && tid < 36) gcons[tid - 32] = 0;
        if (tid >= 48 && tid < 50) cnt[tid - 48] = 0;
    }
    __syncthreads();
    if (tid < 128) {   // "1" column, both buffers
        int buf = tid >> 6, b = tid & 63;
        h_pack[buf][((b >> 4) * 9 + 8) * 512 + (b & 15) * 8 + 2] = (_Float16)1.f;
    }
    if (tid < 128) {   // x(0) into buf1 (h(-1) parity: MFMA(0) reads buf[1])
        int b = tid >> 1, jj = tid & 1;
        h_pack[1][((b >> 4) * 9 + 8) * 512 + (b & 15) * 8 + jj] =
            (_Float16)x_input[(row0 + b) * 2 + jj];
    }
    __syncthreads();   // last barrier; roles diverge below

    auto ldacq = [&](int* p) {
        return __hip_atomic_load(p, __ATOMIC_ACQUIRE, __HIP_MEMORY_SCOPE_WORKGROUP);
    };
    auto strel = [&](int* p, int v) {
        if (L == 0)
            __hip_atomic_store(p, v, __ATOMIC_RELEASE, __HIP_MEMORY_SCOPE_WORKGROUP);
    };

    if (w < 4) {
        // ================= MFMA role (waves 0-3) =================
        constexpr int ord9[9] = {0, 2, 4, 6, 1, 3, 5, 7, 8};
#pragma unroll 1
        for (int t = 0; t < SEQ + TLEN; t++) {
            const _Float16* __restrict__ Wt =
                ((t < SEQ) ? g_w_enc : (t == SEQ) ? g_w_dec0 : g_w_deff)
                + w * 73728;
            const _Float16* __restrict__ hp = h_pack[(t + 1) & 1];  // h(t-1)
#pragma unroll 1
            for (int qi = 0; qi < 4; qi++) {
                const _Float16* __restrict__ Wq = Wt + qi * 18432;
                floatx4 acc[4][4];   // [g][nt]
                if (qi == 0) {
                    // gated, availability-ordered kt loop
                    int pf = ldacq(&hf[0]);
#pragma unroll
                    for (int idx = 0; idx < 9; idx++) {
                        int kt = ord9[idx];
                        int pfn = 0;
                        if (idx < 8) pfn = ldacq(&hf[ord9[idx + 1]]);
                        while (pf < t) {
                            __builtin_amdgcn_s_sleep(1);
                            pf = ldacq(&hf[kt]);
                        }
                        __builtin_amdgcn_sched_barrier(0);
                        half8 B[4];
#pragma unroll
                        for (int nt = 0; nt < 4; nt++)
                            B[nt] = *(const half8*)&hp[(nt * 9 + kt) * 512 + aoff];
#pragma unroll
                        for (int g = 0; g < 4; g++) {
                            half8 Aw = *(const half8*)&Wq[(kt * 4 + g) * 512 + aoff];
                            if (kt == 0) {
#pragma unroll
                                for (int nt = 0; nt < 4; nt++)
                                    acc[g][nt] = __builtin_amdgcn_mfma_f32_16x16x32_f16(
                                        Aw, B[nt], (floatx4)(0.f), 0, 0, 0);
                            } else {
#pragma unroll
                                for (int nt = 0; nt < 4; nt++)
                                    acc[g][nt] = __builtin_amdgcn_mfma_f32_16x16x32_f16(
                                        Aw, B[nt], acc[g][nt], 0, 0, 0);
                            }
                        }
                        pf = pfn;
                    }
                } else {
                    // h fully ready (quarter 0 gated all tiles)
#pragma unroll
                    for (int kt = 0; kt < 9; kt++) {
                        half8 B[4];
#pragma unroll
                        for (int nt = 0; nt < 4; nt++)
                            B[nt] = *(const half8*)&hp[(nt * 9 + kt) * 512 + aoff];
#pragma unroll
                        for (int g = 0; g < 4; g++) {
                            half8 Aw = *(const half8*)&Wq[(kt * 4 + g) * 512 + aoff];
                            if (kt == 0) {
#pragma unroll
                                for (int nt = 0; nt < 4; nt++)
                                    acc[g][nt] = __builtin_amdgcn_mfma_f32_16x16x32_f16(
                                        Aw, B[nt], (floatx4)(0.f), 0, 0, 0);
                            } else {
#pragma unroll
                                for (int nt = 0; nt < 4; nt++)
                                    acc[g][nt] = __builtin_amdgcn_mfma_f32_16x16x32_f16(
                                        Aw, B[nt], acc[g][nt], 0, 0, 0);
                            }
                        }
                    }
                }
                // ring space gate (2-deep): previous occupant consumed?
                const int seq = 4 * t + qi;
                while (ldacq(&gcons[w]) < seq - 1) __builtin_amdgcn_s_sleep(1);
                __builtin_amdgcn_sched_barrier(0);
                _Float16* gc = &gates_ring[seq & 1][w][0];
#pragma unroll
                for (int g = 0; g < 4; g++)
#pragma unroll
                    for (int nt = 0; nt < 4; nt++) {
                        half4 hv;
#pragma unroll
                        for (int r4 = 0; r4 < 4; r4++)
                            hv[r4] = (_Float16)acc[g][nt][r4];
                        *(half4*)&gc[(g * 4 + nt) * 272 + lb] = hv;
                    }
                strel(&gprod[w], seq + 1);
            }
        }
    } else {
        // ================= EW role (waves 4-7) =================
        const int e = w - 4;
        const float2 bo2 = make_float2(b_out[0], b_out[1]);
        // wo for this lane's cells: c = 64e + 32r + 16u + 4q + r4, qi=2r+u
        float wo_reg[4][4][2];
#pragma unroll
        for (int qi = 0; qi < 4; qi++)
#pragma unroll
            for (int r4 = 0; r4 < 4; r4++) {
                int c = 64 * e + 32 * (qi >> 1) + 16 * (qi & 1) + 4 * q + r4;
                wo_reg[qi][r4][0] = (float)g_wout[c];
                wo_reg[qi][r4][1] = (float)g_wout[256 + c];
            }
        float c_st[4][4][4];   // [qi][nt][r4]
#pragma unroll
        for (int qi = 0; qi < 4; qi++)
#pragma unroll
            for (int nt = 0; nt < 4; nt++)
#pragma unroll
                for (int r4 = 0; r4 < 4; r4++) c_st[qi][nt][r4] = 0.f;

#pragma unroll 1
        for (int t = 0; t < SEQ + TLEN; t++) {
            const int par = t & 1;
            _Float16* __restrict__ hn = h_pack[par];    // h(t)
            const bool dec = (t >= SEQ);
            float po[4][2];
#pragma unroll
            for (int nt = 0; nt < 4; nt++) { po[nt][0] = 0.f; po[nt][1] = 0.f; }

#pragma unroll 1
            for (int qi = 0; qi < 4; qi++) {
                const int seq = 4 * t + qi;
                const int r = qi >> 1, u = qi & 1;
                while (ldacq(&gprod[e]) < seq + 1) __builtin_amdgcn_s_sleep(1);
                __builtin_amdgcn_sched_barrier(0);
                const _Float16* gc = &gates_ring[seq & 1][e][0];
                half4 gh[4][4];   // [g][nt]
#pragma unroll
                for (int g = 0; g < 4; g++)
#pragma unroll
                    for (int nt = 0; nt < 4; nt++)
                        gh[g][nt] = *(const half4*)&gc[(g * 4 + nt) * 272 + lb];
#pragma unroll
                for (int nt = 0; nt < 4; nt++) {
                    half4 hv4;
                    float hvf[4];
#pragma unroll
                    for (int r4 = 0; r4 < 4; r4++) {
                        float ai = (float)gh[0][nt][r4];
                        float af = (float)gh[1][nt][r4];
                        float ag = (float)gh[2][nt][r4];
                        float ao = (float)gh[3][nt][r4];
                        float eI = __builtin_amdgcn_exp2f(-ai);
                        float eG = __builtin_amdgcn_exp2f(-ag);
                        float eF = __builtin_amdgcn_exp2f(-af);
                        float eO = __builtin_amdgcn_exp2f(-ao);
                        float ig = (1.f - eG) *
                            __builtin_amdgcn_rcpf((1.f + eI) * (1.f + eG));
                        float fs = __builtin_amdgcn_rcpf(1.f + eF);
                        float cn = fmaf(fs, c_st[qi][nt][r4], ig);
                        c_st[qi][nt][r4] = cn;
                        float cnc = fminf(fmaxf(cn, -12.f), 12.f);
                        float eC = __builtin_amdgcn_exp2f(-LOG2E2 * cnc);
                        float hv = (1.f - eC) *
                            __builtin_amdgcn_rcpf((1.f + eO) * (1.f + eC));
                        hvf[r4] = hv;
                        hv4[r4] = (_Float16)hv;
                    }
                    // cell = 64e+32r+16u+4q+r4 -> kt=2e+r, q2=2u+(q>>1), j0=4(q&1)
                    *(half4*)&hn[(nt * 9 + 2 * e + r) * 512 +
                                 (2 * u + (q >> 1)) * 128 + l16 * 8 + 4 * (q & 1)] = hv4;
                    if (dec) {
#pragma unroll
                        for (int r4 = 0; r4 < 4; r4++) {
                            po[nt][0] = fmaf(hvf[r4], wo_reg[qi][r4][0], po[nt][0]);
                            po[nt][1] = fmaf(hvf[r4], wo_reg[qi][r4][1], po[nt][1]);
                        }
                    }
                }
                if (qi == 1) strel(&hf[2 * e], t + 1);
                else if (qi == 3) strel(&hf[2 * e + 1], t + 1);
                strel(&gcons[e], seq + 1);
            }

            // aug tile (x + bias col) owner: EW wave 0
            if (e == 0) {
                if (t < SEQ) {
                    int srct = (t + 1 < SEQ) ? t + 1 : SEQ - 1;
                    float2 xv = *(const float2*)
                        &x_input[(long)srct * 32768 + (row0 + L) * 2];
                    half2v xh; xh[0] = (_Float16)xv.x; xh[1] = (_Float16)xv.y;
                    *(half2v*)&hn[((L >> 4) * 9 + 8) * 512 + (L & 15) * 8] = xh;
                }
                strel(&hf[8], t + 1);
            }

            // decoder out-projection: 4-wave partial reduce
            if (dec) {
#pragma unroll
                for (int nt = 0; nt < 4; nt++)
#pragma unroll
                    for (int jj = 0; jj < 2; jj++) {
                        float s = po[nt][jj];
                        s += __shfl_xor(s, 16);
                        s += __shfl_xor(s, 32);
                        po[nt][jj] = s;
                    }
                if (q == 0) {
                    float* pl = &partial_lds[par][e * 136];
#pragma unroll
                    for (int nt = 0; nt < 4; nt++) {
                        pl[nt * 16 + l16]      = po[nt][0];
                        pl[68 + nt * 16 + l16] = po[nt][1];
                    }
                }
                __threadfence_block();
                int arr = 0;
                if (L == 0) arr = atomicAdd(&cnt[par], 1);
                arr = __shfl(arr, 0);
                if (arr == 3) {
                    if (L == 0)
                        __hip_atomic_store(&cnt[par], 0, __ATOMIC_RELAXED,
                                           __HIP_MEMORY_SCOPE_WORKGROUP);
                    __threadfence_block();
                    float s0 = bo2.x, s1 = bo2.y;
#pragma unroll
                    for (int e4 = 0; e4 < 4; e4++) {
                        s0 += partial_lds[par][e4 * 136 + L];
                        s1 += partial_lds[par][e4 * 136 + 68 + L];
                    }
                    *(float2*)&out[(long)(t - SEQ) * 32768 + (row0 + L) * 2] =
                        make_float2(s0, s1);
                }
            }
        }
    }
}

extern "C" void kernel_launch(void* const* d_in, const int* in_sizes, int n_in,
                              void* d_out, int out_size, void* d_ws, size_t ws_size,
                              hipStream_t stream) {
    (void)in_sizes; (void)n_in; (void)d_ws; (void)ws_size; (void)out_size;
    const float* x      = (const float*)d_in[0];
    const float* W_emb  = (const float*)d_in[1];
    const float* b_emb  = (const float*)d_in[2];
    const float* W_ih_e = (const float*)d_in[3];
    const float* W_hh_e = (const float*)d_in[4];
    const float* b_enc  = (const float*)d_in[5];
    const float* W_ih_d = (const float*)d_in[6];
    const float* W_hh_d = (const float*)d_in[7];
    const float* b_dec  = (const float*)d_in[8];
    const float* W_out  = (const float*)d_in[9];
    const float* b_out  = (const float*)d_in[10];
    float* outp = (float*)d_out;

    prep_kernel<<<512, 256, 0, stream>>>(W_emb, b_emb, W_ih_e, W_hh_e, b_enc,
                                         W_ih_d, W_hh_d, b_dec, W_out, b_out);
    lstm_fused<<<256, 512, 0, stream>>>(x, b_out, outp);
}

// Round 13
// 650.484 us; speedup vs baseline: 3.1016x; 1.2779x over previous
//
#include <hip/hip_runtime.h>

// lstm_seq2seq fused persistent kernel for MI355X (gfx950), R13.
// = R12 (wave specialization: waves 0-3 MFMA-only, waves 4-7 EW-only,
// gates via 2-deep LDS f16 ring in quarter-step chunks, h parity-buffered,
// dependency-forced pipeline) with ONE fix: the EW quarter loop is fully
// unrolled so c_st/wo_reg/chunk offsets are statically indexed. R12's
// `#pragma unroll 1` + c_st[qi] runtime indexing demoted the cell state to
// scratch -> 700 MB/dispatch HBM spill traffic (the entire regression).
// Carried: A=weights from L2 (per-(wave,quarter,kt) packing), decoder
// feedback folded, K=288 aug ("1"=bias), log2e fold, kt=0 literal-zero C.

#define SEQ  20
#define TLEN 30
#define LOG2E  1.442695041f
#define LOG2E2 2.885390082f

typedef _Float16 half8   __attribute__((ext_vector_type(8)));
typedef _Float16 half4   __attribute__((ext_vector_type(4)));
typedef _Float16 half2v  __attribute__((ext_vector_type(2)));
typedef float    floatx4 __attribute__((ext_vector_type(4)));

// Packed weights. Gate row n (0..1023), k (0..287):
//   g=n>>8 (gate type), rem=n&255, pw=rem>>6 (MFMA wave), r=(rem>>5)&1,
//   u=(rem>>4)&1, qi=2r+u (quarter), l16=n&15; kt=k>>5, q=(k>>3)&3, j8=k&7
//   dst = (((pw*4+qi)*9 + kt)*4 + g)*512 + q*128 + l16*8 + j8
__device__ _Float16 g_w_enc[1024 * 288];
__device__ _Float16 g_w_dec0[1024 * 288];
__device__ _Float16 g_w_deff[1024 * 288];
__device__ _Float16 g_wout[512];           // W_out [2][256] f16 (unscaled)

__global__ void prep_kernel(const float* __restrict__ W_emb,
                            const float* __restrict__ b_emb,
                            const float* __restrict__ W_ih_enc,
                            const float* __restrict__ W_hh_enc,
                            const float* __restrict__ b_enc,
                            const float* __restrict__ W_ih_dec,
                            const float* __restrict__ W_hh_dec,
                            const float* __restrict__ b_dec,
                            const float* __restrict__ W_out,
                            const float* __restrict__ b_out) {
    int gid = blockIdx.x * blockDim.x + threadIdx.x;
    int stride = gridDim.x * blockDim.x;
    for (int s = gid; s < 1024 * 288; s += stride) {
        int n = s / 288, k = s - n * 288;
        int g = n >> 8, rem = n & 255, l16 = n & 15;
        int pw = rem >> 6, r = (rem >> 5) & 1, u = (rem >> 4) & 1;
        int qi = 2 * r + u;
        int kt = k >> 5, q = (k >> 3) & 3, j8 = k & 7;
        int dst = (((pw * 4 + qi) * 9 + kt) * 4 + g) * 512 + q * 128 + l16 * 8 + j8;
        float sc = (g == 2) ? LOG2E2 : LOG2E;
        float fe = 0.f, fd = 0.f, ff = 0.f;
        if (k < 256) {
            fe = W_hh_enc[n * 256 + k];
            fd = W_hh_dec[n * 256 + k];
            ff = fd + W_ih_dec[2 * n] * W_out[k]
                    + W_ih_dec[2 * n + 1] * W_out[256 + k];
        } else {
            int kp = k - 256;
            if (kp < 2) {
                fd = W_ih_dec[2 * n + kp];
                const float* wr = &W_ih_enc[n * 64];
                for (int e = 0; e < 64; e++) fe = fmaf(wr[e], W_emb[2 * e + kp], fe);
            } else if (kp == 2) {
                fd = b_dec[n];
                ff = b_dec[n] + W_ih_dec[2 * n] * b_out[0]
                              + W_ih_dec[2 * n + 1] * b_out[1];
                fe = b_enc[n];
                const float* wr = &W_ih_enc[n * 64];
                for (int e = 0; e < 64; e++) fe = fmaf(wr[e], b_emb[e], fe);
            }
        }
        g_w_enc[dst]  = (_Float16)(fe * sc);
        g_w_dec0[dst] = (_Float16)(fd * sc);
        g_w_deff[dst] = (_Float16)(ff * sc);
    }
    if (gid < 512) g_wout[gid] = (_Float16)W_out[gid];
}

__global__ __launch_bounds__(512, 2) void lstm_fused(
        const float* __restrict__ x_input,    // [20][16384][2]
        const float* __restrict__ b_out,      // [2]
        float* __restrict__ out)              // [30][16384][2]
{
    __shared__ __align__(16) _Float16 h_pack[2][18432];        // 73728 B
    __shared__ __align__(16) _Float16 gates_ring[2][4][4352];  // 69632 B
    __shared__ __align__(16) float    partial_lds[2][4 * 136]; // 4352 B
    __shared__ int hf[9];      // h kt-tile version flags (EW -> MFMA)
    __shared__ int gprod[4];   // chunks produced per pair (MFMA -> EW)
    __shared__ int gcons[4];   // chunks consumed per pair (EW -> MFMA)
    __shared__ int cnt[2];     // out-proj arrival counters per parity

    const int tid = threadIdx.x;
    const int w   = tid >> 6;
    const int L   = tid & 63;
    const int l16 = L & 15;
    const int q   = L >> 4;
    const long row0 = (long)blockIdx.x * 64;
    const int aoff = q * 128 + l16 * 8;
    const int lb   = q * 68 + l16 * 4;

    // ---- init ----
    {
        int* hz = (int*)&h_pack[0][0];
        for (int idx = tid; idx < 18432; idx += 512) hz[idx] = 0;  // both bufs
        if (tid < 9) hf[tid] = 0;
        if (tid >= 16 && tid < 20) gprod[tid - 16] = 0;
        if (tid >= 32 && tid < 36) gcons[tid - 32] = 0;
        if (tid >= 48 && tid < 50) cnt[tid - 48] = 0;
    }
    __syncthreads();
    if (tid < 128) {   // "1" column, both buffers
        int buf = tid >> 6, b = tid & 63;
        h_pack[buf][((b >> 4) * 9 + 8) * 512 + (b & 15) * 8 + 2] = (_Float16)1.f;
    }
    if (tid < 128) {   // x(0) into buf1 (MFMA(0) reads buf[1])
        int b = tid >> 1, jj = tid & 1;
        h_pack[1][((b >> 4) * 9 + 8) * 512 + (b & 15) * 8 + jj] =
            (_Float16)x_input[(row0 + b) * 2 + jj];
    }
    __syncthreads();   // last barrier; roles diverge below

    auto ldacq = [&](int* p) {
        return __hip_atomic_load(p, __ATOMIC_ACQUIRE, __HIP_MEMORY_SCOPE_WORKGROUP);
    };
    auto strel = [&](int* p, int v) {
        if (L == 0)
            __hip_atomic_store(p, v, __ATOMIC_RELEASE, __HIP_MEMORY_SCOPE_WORKGROUP);
    };

    if (w < 4) {
        // ================= MFMA role (waves 0-3) =================
        constexpr int ord9[9] = {0, 2, 4, 6, 1, 3, 5, 7, 8};
#pragma unroll 1
        for (int t = 0; t < SEQ + TLEN; t++) {
            const _Float16* __restrict__ Wt =
                ((t < SEQ) ? g_w_enc : (t == SEQ) ? g_w_dec0 : g_w_deff)
                + w * 73728;
            const _Float16* __restrict__ hp = h_pack[(t + 1) & 1];  // h(t-1)
#pragma unroll 1
            for (int qi = 0; qi < 4; qi++) {
                const _Float16* __restrict__ Wq = Wt + qi * 18432;
                floatx4 acc[4][4];   // [g][nt] - statically indexed below
                if (qi == 0) {
                    int pf = ldacq(&hf[0]);
#pragma unroll
                    for (int idx = 0; idx < 9; idx++) {
                        int kt = ord9[idx];
                        int pfn = 0;
                        if (idx < 8) pfn = ldacq(&hf[ord9[idx + 1]]);
                        while (pf < t) {
                            __builtin_amdgcn_s_sleep(1);
                            pf = ldacq(&hf[kt]);
                        }
                        __builtin_amdgcn_sched_barrier(0);
                        half8 B[4];
#pragma unroll
                        for (int nt = 0; nt < 4; nt++)
                            B[nt] = *(const half8*)&hp[(nt * 9 + kt) * 512 + aoff];
#pragma unroll
                        for (int g = 0; g < 4; g++) {
                            half8 Aw = *(const half8*)&Wq[(kt * 4 + g) * 512 + aoff];
                            if (kt == 0) {
#pragma unroll
                                for (int nt = 0; nt < 4; nt++)
                                    acc[g][nt] = __builtin_amdgcn_mfma_f32_16x16x32_f16(
                                        Aw, B[nt], (floatx4)(0.f), 0, 0, 0);
                            } else {
#pragma unroll
                                for (int nt = 0; nt < 4; nt++)
                                    acc[g][nt] = __builtin_amdgcn_mfma_f32_16x16x32_f16(
                                        Aw, B[nt], acc[g][nt], 0, 0, 0);
                            }
                        }
                        pf = pfn;
                    }
                } else {
#pragma unroll
                    for (int kt = 0; kt < 9; kt++) {
                        half8 B[4];
#pragma unroll
                        for (int nt = 0; nt < 4; nt++)
                            B[nt] = *(const half8*)&hp[(nt * 9 + kt) * 512 + aoff];
#pragma unroll
                        for (int g = 0; g < 4; g++) {
                            half8 Aw = *(const half8*)&Wq[(kt * 4 + g) * 512 + aoff];
                            if (kt == 0) {
#pragma unroll
                                for (int nt = 0; nt < 4; nt++)
                                    acc[g][nt] = __builtin_amdgcn_mfma_f32_16x16x32_f16(
                                        Aw, B[nt], (floatx4)(0.f), 0, 0, 0);
                            } else {
#pragma unroll
                                for (int nt = 0; nt < 4; nt++)
                                    acc[g][nt] = __builtin_amdgcn_mfma_f32_16x16x32_f16(
                                        Aw, B[nt], acc[g][nt], 0, 0, 0);
                            }
                        }
                    }
                }
                const int seq = 4 * t + qi;
                while (ldacq(&gcons[w]) < seq - 1) __builtin_amdgcn_s_sleep(1);
                __builtin_amdgcn_sched_barrier(0);
                _Float16* gc = &gates_ring[seq & 1][w][0];
#pragma unroll
                for (int g = 0; g < 4; g++)
#pragma unroll
                    for (int nt = 0; nt < 4; nt++) {
                        half4 hv;
#pragma unroll
                        for (int r4 = 0; r4 < 4; r4++)
                            hv[r4] = (_Float16)acc[g][nt][r4];
                        *(half4*)&gc[(g * 4 + nt) * 272 + lb] = hv;
                    }
                strel(&gprod[w], seq + 1);
            }
        }
    } else {
        // ================= EW role (waves 4-7) =================
        const int e = w - 4;
        const float2 bo2 = make_float2(b_out[0], b_out[1]);
        float wo_reg[4][4][2];   // [qi][r4][jj] - static after unroll
#pragma unroll
        for (int qi = 0; qi < 4; qi++)
#pragma unroll
            for (int r4 = 0; r4 < 4; r4++) {
                int c = 64 * e + 32 * (qi >> 1) + 16 * (qi & 1) + 4 * q + r4;
                wo_reg[qi][r4][0] = (float)g_wout[c];
                wo_reg[qi][r4][1] = (float)g_wout[256 + c];
            }
        float c_st[4][4][4];   // [qi][nt][r4] - static after unroll
#pragma unroll
        for (int qi = 0; qi < 4; qi++)
#pragma unroll
            for (int nt = 0; nt < 4; nt++)
#pragma unroll
                for (int r4 = 0; r4 < 4; r4++) c_st[qi][nt][r4] = 0.f;

#pragma unroll 1
        for (int t = 0; t < SEQ + TLEN; t++) {
            const int par = t & 1;
            _Float16* __restrict__ hn = h_pack[par];    // h(t)
            const bool dec = (t >= SEQ);
            float po[4][2];
#pragma unroll
            for (int nt = 0; nt < 4; nt++) { po[nt][0] = 0.f; po[nt][1] = 0.f; }

            // FULLY UNROLLED quarter loop: c_st/wo_reg statically indexed
#pragma unroll
            for (int qi = 0; qi < 4; qi++) {
                const int seq = 4 * t + qi;
                const int r = qi >> 1, u = qi & 1;
                while (ldacq(&gprod[e]) < seq + 1) __builtin_amdgcn_s_sleep(1);
                __builtin_amdgcn_sched_barrier(0);
                const _Float16* gc = &gates_ring[seq & 1][e][0];
                half4 gh[4][4];   // [g][nt]
#pragma unroll
                for (int g = 0; g < 4; g++)
#pragma unroll
                    for (int nt = 0; nt < 4; nt++)
                        gh[g][nt] = *(const half4*)&gc[(g * 4 + nt) * 272 + lb];
#pragma unroll
                for (int nt = 0; nt < 4; nt++) {
                    half4 hv4;
                    float hvf[4];
#pragma unroll
                    for (int r4 = 0; r4 < 4; r4++) {
                        float ai = (float)gh[0][nt][r4];
                        float af = (float)gh[1][nt][r4];
                        float ag = (float)gh[2][nt][r4];
                        float ao = (float)gh[3][nt][r4];
                        float eI = __builtin_amdgcn_exp2f(-ai);
                        float eG = __builtin_amdgcn_exp2f(-ag);
                        float eF = __builtin_amdgcn_exp2f(-af);
                        float eO = __builtin_amdgcn_exp2f(-ao);
                        float ig = (1.f - eG) *
                            __builtin_amdgcn_rcpf((1.f + eI) * (1.f + eG));
                        float fs = __builtin_amdgcn_rcpf(1.f + eF);
                        float cn = fmaf(fs, c_st[qi][nt][r4], ig);
                        c_st[qi][nt][r4] = cn;
                        float cnc = fminf(fmaxf(cn, -12.f), 12.f);
                        float eC = __builtin_amdgcn_exp2f(-LOG2E2 * cnc);
                        float hv = (1.f - eC) *
                            __builtin_amdgcn_rcpf((1.f + eO) * (1.f + eC));
                        hvf[r4] = hv;
                        hv4[r4] = (_Float16)hv;
                    }
                    *(half4*)&hn[(nt * 9 + 2 * e + r) * 512 +
                                 (2 * u + (q >> 1)) * 128 + l16 * 8 + 4 * (q & 1)] = hv4;
                    if (dec) {
#pragma unroll
                        for (int r4 = 0; r4 < 4; r4++) {
                            po[nt][0] = fmaf(hvf[r4], wo_reg[qi][r4][0], po[nt][0]);
                            po[nt][1] = fmaf(hvf[r4], wo_reg[qi][r4][1], po[nt][1]);
                        }
                    }
                }
                if (qi == 1) strel(&hf[2 * e], t + 1);
                else if (qi == 3) strel(&hf[2 * e + 1], t + 1);
                strel(&gcons[e], seq + 1);
            }

            // aug tile (x + bias col) owner: EW wave 0
            if (e == 0) {
                if (t < SEQ) {
                    int srct = (t + 1 < SEQ) ? t + 1 : SEQ - 1;
                    float2 xv = *(const float2*)
                        &x_input[(long)srct * 32768 + (row0 + L) * 2];
                    half2v xh; xh[0] = (_Float16)xv.x; xh[1] = (_Float16)xv.y;
                    *(half2v*)&hn[((L >> 4) * 9 + 8) * 512 + (L & 15) * 8] = xh;
                }
                strel(&hf[8], t + 1);
            }

            // decoder out-projection: 4-wave partial reduce
            if (dec) {
#pragma unroll
                for (int nt = 0; nt < 4; nt++)
#pragma unroll
                    for (int jj = 0; jj < 2; jj++) {
                        float s = po[nt][jj];
                        s += __shfl_xor(s, 16);
                        s += __shfl_xor(s, 32);
                        po[nt][jj] = s;
                    }
                if (q == 0) {
                    float* pl = &partial_lds[par][e * 136];
#pragma unroll
                    for (int nt = 0; nt < 4; nt++) {
                        pl[nt * 16 + l16]      = po[nt][0];
                        pl[68 + nt * 16 + l16] = po[nt][1];
                    }
                }
                __threadfence_block();
                int arr = 0;
                if (L == 0) arr = atomicAdd(&cnt[par], 1);
                arr = __shfl(arr, 0);
                if (arr == 3) {
                    if (L == 0)
                        __hip_atomic_store(&cnt[par], 0, __ATOMIC_RELAXED,
                                           __HIP_MEMORY_SCOPE_WORKGROUP);
                    __threadfence_block();
                    float s0 = bo2.x, s1 = bo2.y;
#pragma unroll
                    for (int e4 = 0; e4 < 4; e4++) {
                        s0 += partial_lds[par][e4 * 136 + L];
                        s1 += partial_lds[par][e4 * 136 + 68 + L];
                    }
                    *(float2*)&out[(long)(t - SEQ) * 32768 + (row0 + L) * 2] =
                        make_float2(s0, s1);
                }
            }
        }
    }
}

extern "C" void kernel_launch(void* const* d_in, const int* in_sizes, int n_in,
                              void* d_out, int out_size, void* d_ws, size_t ws_size,
                              hipStream_t stream) {
    (void)in_sizes; (void)n_in; (void)d_ws; (void)ws_size; (void)out_size;
    const float* x      = (const float*)d_in[0];
    const float* W_emb  = (const float*)d_in[1];
    const float* b_emb  = (const float*)d_in[2];
    const float* W_ih_e = (const float*)d_in[3];
    const float* W_hh_e = (const float*)d_in[4];
    const float* b_enc  = (const float*)d_in[5];
    const float* W_ih_d = (const float*)d_in[6];
    const float* W_hh_d = (const float*)d_in[7];
    const float* b_dec  = (const float*)d_in[8];
    const float* W_out  = (const float*)d_in[9];
    const float* b_out  = (const float*)d_in[10];
    float* outp = (float*)d_out;

    prep_kernel<<<512, 256, 0, stream>>>(W_emb, b_emb, W_ih_e, W_hh_e, b_enc,
                                         W_ih_d, W_hh_d, b_dec, W_out, b_out);
    lstm_fused<<<256, 512, 0, stream>>>(x, b_out, outp);
}